// Round 1
// baseline (1575.448 us; speedup 1.0000x reference)
//
#include <hip/hip_runtime.h>
#include <hip/hip_bf16.h>

// SNN forward: conv1(3->64,3x3,p1) -> IF -> pool2 -> conv2(64->64) -> IF -> pool2
//              -> fc1(16384->4096) -> IF -> fc2(4096->10) -> IF -> mean over T
// T=8 N=32 IMG=64. All fp32, deterministic accumulation order (no atomics):
// spikes are hard thresholds; one flipped spike = 0.125 output error.

#define T_STEPS 8
#define NB      32
#define CMID    64

// ---------------------------------------------------------------- w2 transpose
// w2[co][ci][ky][kx] -> w2t[ci*9+ky*3+kx][co]  (so per-tap 64 weights are
// contiguous and wave-uniform -> scalar loads in conv2)
__global__ void k_w2t(const float* __restrict__ w2, float* __restrict__ w2t) {
    int idx = blockIdx.x * 256 + threadIdx.x;
    if (idx < 64 * 576) {
        int co = idx & 63;
        int q  = idx >> 6;              // ci*9+ky*3+kx
        w2t[q * 64 + co] = w2[co * 576 + q];
    }
}

// ------------------------------------------------- conv1 + IF + maxpool fused
// thread = (n, co-group of 8, pooled pixel). Loops t sequentially (IF state in
// regs). Writes spikes1[t][n][co][ph][pw] (32x32).
__global__ __launch_bounds__(256) void k_conv1_if_pool(
        const float* __restrict__ x, const float* __restrict__ w1,
        float* __restrict__ spk1) {
    int b   = blockIdx.x;               // 1024 = 32n * 8cog * 4pht
    int n   = b >> 5;
    int cog = (b >> 2) & 7;
    int pht = b & 3;
    int tid = threadIdx.x;
    int pw  = tid & 31;
    int ph  = pht * 8 + (tid >> 5);
    int ih0 = 2 * ph - 1, iw0 = 2 * pw - 1;

    float v[8][4];
#pragma unroll
    for (int a = 0; a < 8; a++)
#pragma unroll
        for (int p = 0; p < 4; p++) v[a][p] = 0.f;

    for (int t = 0; t < T_STEPS; t++) {
        const float* xb = x + (size_t)(t * NB + n) * 3 * 4096;
        float patch[3][4][4];
#pragma unroll
        for (int ci = 0; ci < 3; ci++)
#pragma unroll
            for (int dy = 0; dy < 4; dy++) {
                int ih = ih0 + dy;
                bool rok = ((unsigned)ih < 64u);
#pragma unroll
                for (int dx = 0; dx < 4; dx++) {
                    int iw = iw0 + dx;
                    patch[ci][dy][dx] = (rok && ((unsigned)iw < 64u))
                                            ? xb[ci * 4096 + ih * 64 + iw] : 0.f;
                }
            }
#pragma unroll
        for (int c8 = 0; c8 < 8; c8++) {
            int co = cog * 8 + c8;
            const float* wc = w1 + co * 27;   // wave-uniform -> s_load
            float a0 = 0.f, a1 = 0.f, a2 = 0.f, a3 = 0.f;
#pragma unroll
            for (int ci = 0; ci < 3; ci++)
#pragma unroll
                for (int ky = 0; ky < 3; ky++)
#pragma unroll
                    for (int kx = 0; kx < 3; kx++) {
                        float w = wc[ci * 9 + ky * 3 + kx];
                        a0 += w * patch[ci][ky][kx];
                        a1 += w * patch[ci][ky][kx + 1];
                        a2 += w * patch[ci][ky + 1][kx];
                        a3 += w * patch[ci][ky + 1][kx + 1];
                    }
            // IF (v+=x; s=(v>=1); hard reset) + 2x2 max-pool
            float s0, s1, s2, s3;
            v[c8][0] += a0; s0 = (v[c8][0] >= 1.f) ? 1.f : 0.f; if (s0 > 0.f) v[c8][0] = 0.f;
            v[c8][1] += a1; s1 = (v[c8][1] >= 1.f) ? 1.f : 0.f; if (s1 > 0.f) v[c8][1] = 0.f;
            v[c8][2] += a2; s2 = (v[c8][2] >= 1.f) ? 1.f : 0.f; if (s2 > 0.f) v[c8][2] = 0.f;
            v[c8][3] += a3; s3 = (v[c8][3] >= 1.f) ? 1.f : 0.f; if (s3 > 0.f) v[c8][3] = 0.f;
            float sm = fmaxf(fmaxf(s0, s1), fmaxf(s2, s3));
            spk1[((size_t)(t * NB + n) * CMID + co) * 1024 + ph * 32 + pw] = sm;
        }
    }
}

// ------------------------------------------------------------- conv2 (pre-act)
// thread = one spatial pixel of one (t,n), all 64 co accumulators in VGPRs.
// Weights via w2t: per-tap 64 contiguous floats, wave-uniform index -> SGPRs.
__global__ __launch_bounds__(256) void k_conv2(
        const float* __restrict__ spk1, const float* __restrict__ w2t,
        float* __restrict__ buf2) {
    int b  = blockIdx.x;                // 1024 = 256tn * 4ht
    int tn = b >> 2;
    int ht = b & 3;
    int tid = threadIdx.x;
    int w = tid & 31;
    int h = ht * 8 + (tid >> 5);

    float acc[64];
#pragma unroll
    for (int i = 0; i < 64; i++) acc[i] = 0.f;

    const float* ib = spk1 + (size_t)tn * CMID * 1024;
    for (int ci = 0; ci < 64; ci++) {
        const float* ip = ib + ci * 1024;
        float p[3][3];
#pragma unroll
        for (int dy = 0; dy < 3; dy++) {
            int hh = h - 1 + dy;
            bool rok = ((unsigned)hh < 32u);
#pragma unroll
            for (int dx = 0; dx < 3; dx++) {
                int ww = w - 1 + dx;
                p[dy][dx] = (rok && ((unsigned)ww < 32u)) ? ip[hh * 32 + ww] : 0.f;
            }
        }
#pragma unroll
        for (int ky = 0; ky < 3; ky++)
#pragma unroll
            for (int kx = 0; kx < 3; kx++) {
                float xv = p[ky][kx];
                const float* wp = w2t + ((ci * 3 + ky) * 3 + kx) * 64;
#pragma unroll
                for (int co = 0; co < 64; co++) acc[co] += wp[co] * xv;
            }
    }
    float* ob = buf2 + (size_t)tn * CMID * 1024 + h * 32 + w;
#pragma unroll
    for (int co = 0; co < 64; co++) ob[co * 1024] = acc[co];
}

// ------------------------------------------------------- IF + maxpool stage 2
__global__ void k_if_pool2(const float* __restrict__ buf2,
                           float* __restrict__ spk2) {
    int idx = blockIdx.x * 256 + threadIdx.x;     // 524288
    int pw = idx & 15, ph = (idx >> 4) & 15, c = (idx >> 8) & 63, n = idx >> 14;
    float v0 = 0.f, v1 = 0.f, v2 = 0.f, v3 = 0.f;
    for (int t = 0; t < T_STEPS; t++) {
        const float* bp = buf2 + ((size_t)(t * NB + n) * CMID + c) * 1024
                          + (2 * ph) * 32 + 2 * pw;
        float x0 = bp[0], x1 = bp[1], x2 = bp[32], x3 = bp[33];
        float s0, s1, s2, s3;
        v0 += x0; s0 = (v0 >= 1.f) ? 1.f : 0.f; if (s0 > 0.f) v0 = 0.f;
        v1 += x1; s1 = (v1 >= 1.f) ? 1.f : 0.f; if (s1 > 0.f) v1 = 0.f;
        v2 += x2; s2 = (v2 >= 1.f) ? 1.f : 0.f; if (s2 > 0.f) v2 = 0.f;
        v3 += x3; s3 = (v3 >= 1.f) ? 1.f : 0.f; if (s3 > 0.f) v3 = 0.f;
        spk2[((size_t)(t * NB + n) * CMID + c) * 256 + ph * 16 + pw] =
            fmaxf(fmaxf(s0, s1), fmaxf(s2, s3));
    }
}

// ----------------------------------------------------------------- fc1 GEMM
// C[256 x 4096] = A[256 x 16384] * fc1^T. 64x64 tiles, 4-way K split
// (deterministic reduce in k_fc1_if). LDS tiles stored k-contiguous with
// pad-36 rows so inner loop uses aligned ds_read_b128.
__global__ __launch_bounds__(128) void k_fc1(
        const float* __restrict__ A, const float* __restrict__ Bw,
        float* __restrict__ part) {
    int b  = blockIdx.x;                 // 1024 = 4ks * 4mt * 64nt
    int nt = b & 63;
    int mt = (b >> 6) & 3;
    int ks = b >> 8;
    int m0 = mt * 64, o0 = nt * 64, k0 = ks * 4096;

    __shared__ float As[64][36];
    __shared__ float Bs[64][36];

    int tid  = threadIdx.x;
    int mo   = tid & 15;                 // row within wave tile
    int oo   = tid >> 4;                 // 0..7 col group
    int lr   = tid >> 1;                 // loader row 0..63
    int lh   = tid & 1;                  // loader k-half

    const float* Ar = A  + (size_t)(m0 + lr) * 16384 + k0 + lh * 16;
    const float* Br = Bw + (size_t)(o0 + lr) * 16384 + k0 + lh * 16;

    float acc[4][8];
#pragma unroll
    for (int i = 0; i < 4; i++)
#pragma unroll
        for (int j = 0; j < 8; j++) acc[i][j] = 0.f;

    for (int kt = 0; kt < 128; kt++) {
        float4 av[4], bv[4];
        const float4* a4 = (const float4*)(Ar + kt * 32);
        const float4* b4 = (const float4*)(Br + kt * 32);
#pragma unroll
        for (int j = 0; j < 4; j++) { av[j] = a4[j]; bv[j] = b4[j]; }
        __syncthreads();                 // prev compute done before overwrite
#pragma unroll
        for (int j = 0; j < 4; j++) {
            *(float4*)&As[lr][lh * 16 + 4 * j] = av[j];
            *(float4*)&Bs[lr][lh * 16 + 4 * j] = bv[j];
        }
        __syncthreads();
#pragma unroll
        for (int q = 0; q < 8; q++) {    // 4 k's per q
            float4 ar[4], br[8];
#pragma unroll
            for (int mi = 0; mi < 4; mi++)
                ar[mi] = *(const float4*)&As[mo + 16 * mi][q * 4];
#pragma unroll
            for (int oj = 0; oj < 8; oj++)
                br[oj] = *(const float4*)&Bs[oo + 8 * oj][q * 4];
#pragma unroll
            for (int mi = 0; mi < 4; mi++)
#pragma unroll
                for (int oj = 0; oj < 8; oj++) {
                    acc[mi][oj] += ar[mi].x * br[oj].x;
                    acc[mi][oj] += ar[mi].y * br[oj].y;
                    acc[mi][oj] += ar[mi].z * br[oj].z;
                    acc[mi][oj] += ar[mi].w * br[oj].w;
                }
        }
    }
#pragma unroll
    for (int mi = 0; mi < 4; mi++)
#pragma unroll
        for (int oj = 0; oj < 8; oj++) {
            int m = m0 + mo + 16 * mi;
            int o = o0 + oo + 8 * oj;
            part[((size_t)ks * 256 + m) * 4096 + o] = acc[mi][oj];
        }
}

// ----------------------------------------------- K-split reduce + IF for fc1
__global__ void k_fc1_if(const float* __restrict__ part,
                         float* __restrict__ spk3) {
    int idx = blockIdx.x * 256 + threadIdx.x;   // 131072
    int o = idx & 4095;
    int n = idx >> 12;
    float v = 0.f;
    for (int t = 0; t < T_STEPS; t++) {
        int m = t * NB + n;
        float s = part[(size_t)(0 * 256 + m) * 4096 + o];
        s += part[(size_t)(1 * 256 + m) * 4096 + o];
        s += part[(size_t)(2 * 256 + m) * 4096 + o];
        s += part[(size_t)(3 * 256 + m) * 4096 + o];
        v += s;
        float sp = (v >= 1.f) ? 1.f : 0.f;
        if (sp > 0.f) v = 0.f;
        spk3[(size_t)m * 4096 + o] = sp;
    }
}

// ------------------------------------------------------ fc2 + IF + time-mean
__global__ __launch_bounds__(256) void k_fc2_if_mean(
        const float* __restrict__ spk3, const float* __restrict__ fc2,
        float* __restrict__ out) {
    int b = blockIdx.x;                  // 320 = 32n * 10o
    int n = b / 10, o = b % 10;
    const float* wr = fc2 + o * 4096;
    __shared__ float red[256];
    int tid = threadIdx.x;
    float v = 0.f, cnt = 0.f;
    for (int t = 0; t < T_STEPS; t++) {
        const float* row = spk3 + (size_t)(t * NB + n) * 4096;
        float p = 0.f;
        for (int i = tid; i < 4096; i += 256) p += row[i] * wr[i];
        red[tid] = p;
        __syncthreads();
        for (int s = 128; s > 0; s >>= 1) {
            if (tid < s) red[tid] += red[tid + s];
            __syncthreads();
        }
        if (tid == 0) {
            v += red[0];
            float sp = (v >= 1.f) ? 1.f : 0.f;
            cnt += sp;
            if (sp > 0.f) v = 0.f;
        }
        __syncthreads();
    }
    if (tid == 0) out[n * 10 + o] = cnt * 0.125f;
}

// ---------------------------------------------------------------------- launch
extern "C" void kernel_launch(void* const* d_in, const int* in_sizes, int n_in,
                              void* d_out, int out_size, void* d_ws, size_t ws_size,
                              hipStream_t stream) {
    const float* x   = (const float*)d_in[0];   // [8,32,3,64,64]
    const float* w1  = (const float*)d_in[1];   // [64,3,3,3]
    const float* w2  = (const float*)d_in[2];   // [64,64,3,3]
    const float* fc1 = (const float*)d_in[3];   // [4096,16384]
    const float* fc2 = (const float*)d_in[4];   // [10,4096]
    float* out = (float*)d_out;                 // [32,10]

    float* ws = (float*)d_ws;
    // workspace layout (floats)
    const size_t off_w2t  = 0;                       // 36864
    const size_t off_spk1 = 36864;                   // 16777216
    const size_t off_buf2 = off_spk1 + 16777216;     // 16777216
    const size_t off_spk2 = off_buf2 + 16777216;     // 4194304
    const size_t off_part = off_spk2 + 4194304;      // 4194304
    const size_t off_spk3 = off_part + 4194304;      // 1048576
    float* w2t  = ws + off_w2t;
    float* spk1 = ws + off_spk1;
    float* buf2 = ws + off_buf2;
    float* spk2 = ws + off_spk2;
    float* part = ws + off_part;
    float* spk3 = ws + off_spk3;

    k_w2t<<<144, 256, 0, stream>>>(w2, w2t);
    k_conv1_if_pool<<<1024, 256, 0, stream>>>(x, w1, spk1);
    k_conv2<<<1024, 256, 0, stream>>>(spk1, w2t, buf2);
    k_if_pool2<<<2048, 256, 0, stream>>>(buf2, spk2);
    k_fc1<<<1024, 128, 0, stream>>>(spk2, fc1, part);
    k_fc1_if<<<512, 256, 0, stream>>>(part, spk3);
    k_fc2_if_mean<<<320, 256, 0, stream>>>(spk3, fc2, out);
}

// Round 3
// 950.705 us; speedup vs baseline: 1.6571x; 1.6571x over previous
//
#include <hip/hip_runtime.h>
#include <hip/hip_bf16.h>

// SNN forward: conv1(3->64,3x3,p1) -> IF -> pool2 -> conv2(64->64) -> IF -> pool2
//              -> fc1(16384->4096) -> IF -> fc2(4096->10) -> IF -> mean over T
// T=8 N=32 IMG=64.
// fc1 uses bf16 MFMA: spikes are exactly 0/1 (exact in bf16); fp32 weights
// are 3-way bf16 split (hi+mid+lo, residual <= 2^-24|w|) -> three MFMAs into
// one fp32 accumulator == fp32 dot product to within fp32 rounding noise.
// Everything else stays fp32 with deterministic accumulation order.

#define T_STEPS 8
#define NB      32
#define CMID    64

typedef __bf16 bf16x4 __attribute__((ext_vector_type(4)));
typedef short  s16x8  __attribute__((ext_vector_type(8)));
typedef float  f32x4  __attribute__((ext_vector_type(4)));

struct Split3 { float h, m, l; };   // bf16 values kept as float for assembly
__device__ __forceinline__ Split3 split3(float x) {
    Split3 s;
    __bf16 h = (__bf16)x;
    float r1 = x - (float)h;
    __bf16 m = (__bf16)r1;
    float r2 = r1 - (float)m;
    __bf16 l = (__bf16)r2;
    s.h = (float)h; s.m = (float)m; s.l = (float)l;
    return s;
}

// ---------------------------------------------------------------- w2 transpose
__global__ void k_w2t(const float* __restrict__ w2, float* __restrict__ w2t) {
    int idx = blockIdx.x * 256 + threadIdx.x;
    if (idx < 64 * 576) {
        int co = idx & 63;
        int q  = idx >> 6;              // ci*9+ky*3+kx
        w2t[q * 64 + co] = w2[co * 576 + q];
    }
}

// ------------------------------------------------- conv1 + IF + maxpool fused
__global__ __launch_bounds__(256) void k_conv1_if_pool(
        const float* __restrict__ x, const float* __restrict__ w1,
        float* __restrict__ spk1) {
    int b   = blockIdx.x;               // 1024 = 32n * 8cog * 4pht
    int n   = b >> 5;
    int cog = (b >> 2) & 7;
    int pht = b & 3;
    int tid = threadIdx.x;
    int pw  = tid & 31;
    int ph  = pht * 8 + (tid >> 5);
    int ih0 = 2 * ph - 1, iw0 = 2 * pw - 1;

    float v[8][4];
#pragma unroll
    for (int a = 0; a < 8; a++)
#pragma unroll
        for (int p = 0; p < 4; p++) v[a][p] = 0.f;

    for (int t = 0; t < T_STEPS; t++) {
        const float* xb = x + (size_t)(t * NB + n) * 3 * 4096;
        float patch[3][4][4];
#pragma unroll
        for (int ci = 0; ci < 3; ci++)
#pragma unroll
            for (int dy = 0; dy < 4; dy++) {
                int ih = ih0 + dy;
                bool rok = ((unsigned)ih < 64u);
#pragma unroll
                for (int dx = 0; dx < 4; dx++) {
                    int iw = iw0 + dx;
                    patch[ci][dy][dx] = (rok && ((unsigned)iw < 64u))
                                            ? xb[ci * 4096 + ih * 64 + iw] : 0.f;
                }
            }
#pragma unroll
        for (int c8 = 0; c8 < 8; c8++) {
            int co = cog * 8 + c8;
            const float* wc = w1 + co * 27;   // wave-uniform -> s_load
            float a0 = 0.f, a1 = 0.f, a2 = 0.f, a3 = 0.f;
#pragma unroll
            for (int ci = 0; ci < 3; ci++)
#pragma unroll
                for (int ky = 0; ky < 3; ky++)
#pragma unroll
                    for (int kx = 0; kx < 3; kx++) {
                        float w = wc[ci * 9 + ky * 3 + kx];
                        a0 += w * patch[ci][ky][kx];
                        a1 += w * patch[ci][ky][kx + 1];
                        a2 += w * patch[ci][ky + 1][kx];
                        a3 += w * patch[ci][ky + 1][kx + 1];
                    }
            float s0, s1, s2, s3;
            v[c8][0] += a0; s0 = (v[c8][0] >= 1.f) ? 1.f : 0.f; if (s0 > 0.f) v[c8][0] = 0.f;
            v[c8][1] += a1; s1 = (v[c8][1] >= 1.f) ? 1.f : 0.f; if (s1 > 0.f) v[c8][1] = 0.f;
            v[c8][2] += a2; s2 = (v[c8][2] >= 1.f) ? 1.f : 0.f; if (s2 > 0.f) v[c8][2] = 0.f;
            v[c8][3] += a3; s3 = (v[c8][3] >= 1.f) ? 1.f : 0.f; if (s3 > 0.f) v[c8][3] = 0.f;
            float sm = fmaxf(fmaxf(s0, s1), fmaxf(s2, s3));
            spk1[((size_t)(t * NB + n) * CMID + co) * 1024 + ph * 32 + pw] = sm;
        }
    }
}

// ------------------------------------------------------------- conv2 (pre-act)
__global__ __launch_bounds__(256) void k_conv2(
        const float* __restrict__ spk1, const float* __restrict__ w2t,
        float* __restrict__ buf2) {
    int b  = blockIdx.x;                // 1024 = 256tn * 4ht
    int tn = b >> 2;
    int ht = b & 3;
    int tid = threadIdx.x;
    int w = tid & 31;
    int h = ht * 8 + (tid >> 5);

    float acc[64];
#pragma unroll
    for (int i = 0; i < 64; i++) acc[i] = 0.f;

    const float* ib = spk1 + (size_t)tn * CMID * 1024;
    for (int ci = 0; ci < 64; ci++) {
        const float* ip = ib + ci * 1024;
        float p[3][3];
#pragma unroll
        for (int dy = 0; dy < 3; dy++) {
            int hh = h - 1 + dy;
            bool rok = ((unsigned)hh < 32u);
#pragma unroll
            for (int dx = 0; dx < 3; dx++) {
                int ww = w - 1 + dx;
                p[dy][dx] = (rok && ((unsigned)ww < 32u)) ? ip[hh * 32 + ww] : 0.f;
            }
        }
#pragma unroll
        for (int ky = 0; ky < 3; ky++)
#pragma unroll
            for (int kx = 0; kx < 3; kx++) {
                float xv = p[ky][kx];
                const float* wp = w2t + ((ci * 3 + ky) * 3 + kx) * 64;
#pragma unroll
                for (int co = 0; co < 64; co++) acc[co] += wp[co] * xv;
            }
    }
    float* ob = buf2 + (size_t)tn * CMID * 1024 + h * 32 + w;
#pragma unroll
    for (int co = 0; co < 64; co++) ob[co * 1024] = acc[co];
}

// ------------------------------------------------ IF + maxpool 2 -> bf16 spikes
__global__ void k_if_pool2(const float* __restrict__ buf2,
                           __bf16* __restrict__ spk2) {
    int idx = blockIdx.x * 256 + threadIdx.x;     // 524288
    int pw = idx & 15, ph = (idx >> 4) & 15, c = (idx >> 8) & 63, n = idx >> 14;
    float v0 = 0.f, v1 = 0.f, v2 = 0.f, v3 = 0.f;
    for (int t = 0; t < T_STEPS; t++) {
        const float* bp = buf2 + ((size_t)(t * NB + n) * CMID + c) * 1024
                          + (2 * ph) * 32 + 2 * pw;
        float x0 = bp[0], x1 = bp[1], x2 = bp[32], x3 = bp[33];
        float s0, s1, s2, s3;
        v0 += x0; s0 = (v0 >= 1.f) ? 1.f : 0.f; if (s0 > 0.f) v0 = 0.f;
        v1 += x1; s1 = (v1 >= 1.f) ? 1.f : 0.f; if (s1 > 0.f) v1 = 0.f;
        v2 += x2; s2 = (v2 >= 1.f) ? 1.f : 0.f; if (s2 > 0.f) v2 = 0.f;
        v3 += x3; s3 = (v3 >= 1.f) ? 1.f : 0.f; if (s3 > 0.f) v3 = 0.f;
        spk2[((size_t)(t * NB + n) * CMID + c) * 256 + ph * 16 + pw] =
            (__bf16)fmaxf(fmaxf(s0, s1), fmaxf(s2, s3));
    }
}

// ----------------------------------------------------------- fc1 via bf16 MFMA
// C[256 x 4096] = A[256 x 16384] * W^T.  Grid 512 = 64 o-tiles(64) x 8 ksplit.
// Block: 256 thr (4 waves), tile M=256 x O=64, K-chunk 2048 in k-iters of 64.
// B (fp32 weights) -> hi/mid/lo bf16 staged in LDS in fragment order (lane-
// contiguous 16B -> conflict-free ds_read_b128). A-frags read direct from
// global (8.4 MB bf16, L2/L3-resident) to keep the LDS pipe under the MFMA pipe.
__global__ __launch_bounds__(256) void k_fc1_mfma(
        const short* __restrict__ A,      // spk2 bf16 bits [256][16384]
        const float* __restrict__ W,      // fc1 [4096][16384]
        float* __restrict__ part) {       // [8][256][4096]
    int b  = blockIdx.x;
    int nt = b & 63;
    int ks = b >> 6;
    int o0 = nt * 64;
    int kbase = ks * 2048;

    __shared__ __bf16 Bs[3][2][4][64][8];   // [split][ksub][ot][lane][8] = 24 KB

    int t    = threadIdx.x;
    int lane = t & 63;
    int wv_i = t >> 6;                      // wave id
    int mh   = wv_i >> 1;                   // m half (0: rows 0-127, 1: 128-255)
    int oh   = wv_i & 1;                    // o pair (o-tiles 2oh, 2oh+1)

    // B staging coords: thread t loads row (t>>4), float4 at k=(t&15)*4
    int orow = t >> 4;                      // 0..15
    int k4   = (t & 15) * 4;                // 0..60
    int sS   = k4 >> 5;                     // ksub of staged chunk
    int kg   = (k4 >> 3) & 3;               // k-group -> lane quad
    int ke   = k4 & 7;                      // element offset (0 or 4)
    int ln   = orow + kg * 16;              // frag lane index
    const float* wp0 = W + (size_t)(o0 + orow) * 16384 + kbase + k4;

    // A fragment base: row = mh*128 + i*16 + (lane&15), k = kbase + it*64 + s*32 + quad*8
    const short* ap0 = A + (size_t)(mh * 128 + (lane & 15)) * 16384
                         + kbase + ((lane >> 4) & 3) * 8;

    f32x4 acc[8][2];
#pragma unroll
    for (int i = 0; i < 8; i++)
#pragma unroll
        for (int oi = 0; oi < 2; oi++) acc[i][oi] = (f32x4){0.f, 0.f, 0.f, 0.f};

    float4 wv[4];
#pragma unroll
    for (int j = 0; j < 4; j++) wv[j] = *(const float4*)(wp0 + (size_t)j * 262144);

    for (int it = 0; it < 32; ++it) {
        __syncthreads();                    // prev iter's Bs reads done
#pragma unroll
        for (int j = 0; j < 4; j++) {
            float4 v4 = wv[j];
            Split3 sx = split3(v4.x), sy = split3(v4.y),
                   sz = split3(v4.z), sw = split3(v4.w);
            bf16x4 h4 = {(__bf16)sx.h, (__bf16)sy.h, (__bf16)sz.h, (__bf16)sw.h};
            bf16x4 m4 = {(__bf16)sx.m, (__bf16)sy.m, (__bf16)sz.m, (__bf16)sw.m};
            bf16x4 l4 = {(__bf16)sx.l, (__bf16)sy.l, (__bf16)sz.l, (__bf16)sw.l};
            *(bf16x4*)&Bs[0][sS][j][ln][ke] = h4;
            *(bf16x4*)&Bs[1][sS][j][ln][ke] = m4;
            *(bf16x4*)&Bs[2][sS][j][ln][ke] = l4;
        }
        __syncthreads();                    // Bs ready
        if (it < 31) {
#pragma unroll
            for (int j = 0; j < 4; j++)     // prefetch next B tile (overlaps MFMA)
                wv[j] = *(const float4*)(wp0 + (size_t)j * 262144 + (it + 1) * 64);
        }
        const short* ait = ap0 + it * 64;
#pragma unroll
        for (int s = 0; s < 2; ++s) {
            s16x8 bb[2][3];
#pragma unroll
            for (int oi = 0; oi < 2; oi++)
#pragma unroll
                for (int sp = 0; sp < 3; sp++)
                    bb[oi][sp] = *(const s16x8*)&Bs[sp][s][2 * oh + oi][lane][0];
            s16x8 av[8];
#pragma unroll
            for (int i = 0; i < 8; i++)
                av[i] = *(const s16x8*)(ait + s * 32 + (size_t)i * 16 * 16384);
#pragma unroll
            for (int i = 0; i < 8; i++)
#pragma unroll
                for (int oi = 0; oi < 2; oi++) {
                    acc[i][oi] = __builtin_amdgcn_mfma_f32_16x16x32_bf16(
                        av[i], bb[oi][0], acc[i][oi], 0, 0, 0);
                    acc[i][oi] = __builtin_amdgcn_mfma_f32_16x16x32_bf16(
                        av[i], bb[oi][1], acc[i][oi], 0, 0, 0);
                    acc[i][oi] = __builtin_amdgcn_mfma_f32_16x16x32_bf16(
                        av[i], bb[oi][2], acc[i][oi], 0, 0, 0);
                }
        }
    }
    // epilogue: C/D layout col=lane&15, row=(lane>>4)*4+reg
    int col = lane & 15;
    int rq  = (lane >> 4) * 4;
#pragma unroll
    for (int i = 0; i < 8; i++)
#pragma unroll
        for (int oi = 0; oi < 2; oi++)
#pragma unroll
            for (int r = 0; r < 4; r++) {
                int m = mh * 128 + i * 16 + rq + r;
                int o = o0 + (2 * oh + oi) * 16 + col;
                part[((size_t)ks * 256 + m) * 4096 + o] = acc[i][oi][r];
            }
}

// ----------------------------------------------- K-split reduce + IF for fc1
__global__ void k_fc1_if(const float* __restrict__ part,
                         float* __restrict__ spk3) {
    int idx = blockIdx.x * 256 + threadIdx.x;   // 131072
    int o = idx & 4095;
    int n = idx >> 12;
    float v = 0.f;
    for (int t = 0; t < T_STEPS; t++) {
        int m = t * NB + n;
        float s = 0.f;
#pragma unroll
        for (int ks = 0; ks < 8; ks++)
            s += part[((size_t)ks * 256 + m) * 4096 + o];
        v += s;
        float sp = (v >= 1.f) ? 1.f : 0.f;
        if (sp > 0.f) v = 0.f;
        spk3[(size_t)m * 4096 + o] = sp;
    }
}

// ------------------------------------------------------ fc2 + IF + time-mean
__global__ __launch_bounds__(256) void k_fc2_if_mean(
        const float* __restrict__ spk3, const float* __restrict__ fc2,
        float* __restrict__ out) {
    int b = blockIdx.x;                  // 320 = 32n * 10o
    int n = b / 10, o = b % 10;
    const float* wr = fc2 + o * 4096;
    __shared__ float red[256];
    int tid = threadIdx.x;
    float v = 0.f, cnt = 0.f;
    for (int t = 0; t < T_STEPS; t++) {
        const float* row = spk3 + (size_t)(t * NB + n) * 4096;
        float p = 0.f;
        for (int i = tid; i < 4096; i += 256) p += row[i] * wr[i];
        red[tid] = p;
        __syncthreads();
        for (int s = 128; s > 0; s >>= 1) {
            if (tid < s) red[tid] += red[tid + s];
            __syncthreads();
        }
        if (tid == 0) {
            v += red[0];
            float sp = (v >= 1.f) ? 1.f : 0.f;
            cnt += sp;
            if (sp > 0.f) v = 0.f;
        }
        __syncthreads();
    }
    if (tid == 0) out[n * 10 + o] = cnt * 0.125f;
}

// ---------------------------------------------------------------------- launch
extern "C" void kernel_launch(void* const* d_in, const int* in_sizes, int n_in,
                              void* d_out, int out_size, void* d_ws, size_t ws_size,
                              hipStream_t stream) {
    const float* x   = (const float*)d_in[0];   // [8,32,3,64,64]
    const float* w1  = (const float*)d_in[1];   // [64,3,3,3]
    const float* w2  = (const float*)d_in[2];   // [64,64,3,3]
    const float* fc1 = (const float*)d_in[3];   // [4096,16384]
    const float* fc2 = (const float*)d_in[4];   // [10,4096]
    float* out = (float*)d_out;                 // [32,10]

    float* ws = (float*)d_ws;
    // workspace layout (float slots)
    const size_t off_w2t  = 0;                       // 36864
    const size_t off_spk1 = 36864;                   // 16777216 floats
    const size_t off_buf2 = off_spk1 + 16777216;     // 16777216 floats
    const size_t off_spk2 = off_buf2 + 16777216;     // slot 4194304 (bf16 uses half)
    const size_t off_spk3 = off_spk2 + 4194304;      // 1048576
    float*  w2t  = ws + off_w2t;
    float*  spk1 = ws + off_spk1;
    float*  buf2 = ws + off_buf2;
    __bf16* spk2 = (__bf16*)(ws + off_spk2);
    // part[8][256][4096] aliases buf2's slot (buf2 dead after k_if_pool2;
    // 33.5 MB <= 67 MB slot)
    float*  part = ws + off_buf2;
    float*  spk3 = ws + off_spk3;

    k_w2t<<<144, 256, 0, stream>>>(w2, w2t);
    k_conv1_if_pool<<<1024, 256, 0, stream>>>(x, w1, spk1);
    k_conv2<<<1024, 256, 0, stream>>>(spk1, w2t, buf2);
    k_if_pool2<<<2048, 256, 0, stream>>>(buf2, spk2);
    k_fc1_mfma<<<512, 256, 0, stream>>>((const short*)spk2, fc1, part);
    k_fc1_if<<<512, 256, 0, stream>>>(part, spk3);
    k_fc2_if_mean<<<320, 256, 0, stream>>>(spk3, fc2, out);
}

// Round 4
// 795.727 us; speedup vs baseline: 1.9799x; 1.1948x over previous
//
#include <hip/hip_runtime.h>
#include <hip/hip_bf16.h>

// SNN forward: conv1(3->64,3x3,p1) -> IF -> pool2 -> conv2(64->64) -> IF -> pool2
//              -> fc1(16384->4096) -> IF -> fc2(4096->10) -> IF -> mean over T
// T=8 N=32 IMG=64.
// conv2 and fc1 use bf16 MFMA: spikes are exactly 0/1 (exact in bf16); fp32
// weights are 3-way bf16 split (hi+mid+lo, residual <= 2^-25|w|) -> three MFMAs
// into one fp32 accumulator == fp32 dot product to within fp32 rounding noise.
// conv2 is tap-decomposed implicit GEMM, fused with IF+maxpool (t-loop in-kernel,
// IF state in VGPRs) -> no pre-activation buffer materialized.

#define T_STEPS 8
#define NB      32
#define CMID    64

typedef __bf16 bf16x2 __attribute__((ext_vector_type(2)));
typedef __bf16 bf16x4 __attribute__((ext_vector_type(4)));
typedef __bf16 bf16x8 __attribute__((ext_vector_type(8)));
typedef short  s16x8  __attribute__((ext_vector_type(8)));
typedef float  f32x4  __attribute__((ext_vector_type(4)));

struct Split3 { float h, m, l; };
__device__ __forceinline__ Split3 split3(float x) {
    Split3 s;
    __bf16 h = (__bf16)x;
    float r1 = x - (float)h;
    __bf16 m = (__bf16)r1;
    float r2 = r1 - (float)m;
    __bf16 l = (__bf16)r2;
    s.h = (float)h; s.m = (float)m; s.l = (float)l;
    return s;
}

// ------------------------------------------------- w2 -> 3-way-split frag order
// w2[co][ci][ky][kx] fp32 -> w2s[ch][tap][kh][oh][sp][lane][j] bf16 where
// co = ch*32+oh*16+(lane&15), ci = kh*32+(lane>>4)*8+j, tap = ky*3+kx.
// This is exactly the MFMA B-fragment order; conv2 blocks memcpy it into LDS.
__global__ void k_w2s(const float* __restrict__ w2, __bf16* __restrict__ w2s) {
    int idx = blockIdx.x * 256 + threadIdx.x;   // 36864 total
    int j    = idx & 7;
    int lane = (idx >> 3) & 63;
    int oh   = (idx >> 9) & 1;
    int kh   = (idx >> 10) & 1;
    int g    = idx >> 11;          // ch*9 + tap, 0..17
    int tap  = g % 9;
    int ch   = g / 9;
    int co = ch * 32 + oh * 16 + (lane & 15);
    int ci = kh * 32 + (lane >> 4) * 8 + j;
    float w = w2[co * 576 + ci * 9 + tap];
    Split3 s = split3(w);
    __bf16* o = w2s + (((size_t)(g * 2 + kh) * 2 + oh) * 3) * 512 + lane * 8 + j;
    o[0]    = (__bf16)s.h;
    o[512]  = (__bf16)s.m;
    o[1024] = (__bf16)s.l;
}

// ------------------------------------------ conv1 + IF + maxpool -> NHWC bf16
// Writes spk1p[tn][h][w][ci] bf16 (ci contiguous -> conv2 A-fragments are
// single 16B loads).
__global__ __launch_bounds__(256) void k_conv1_if_pool(
        const float* __restrict__ x, const float* __restrict__ w1,
        __bf16* __restrict__ spk1p) {
    int b   = blockIdx.x;               // 1024 = 32n * 8cog * 4pht
    int n   = b >> 5;
    int cog = (b >> 2) & 7;
    int pht = b & 3;
    int tid = threadIdx.x;
    int pw  = tid & 31;
    int ph  = pht * 8 + (tid >> 5);
    int ih0 = 2 * ph - 1, iw0 = 2 * pw - 1;

    float v[8][4];
#pragma unroll
    for (int a = 0; a < 8; a++)
#pragma unroll
        for (int p = 0; p < 4; p++) v[a][p] = 0.f;

    for (int t = 0; t < T_STEPS; t++) {
        const float* xb = x + (size_t)(t * NB + n) * 3 * 4096;
        float patch[3][4][4];
#pragma unroll
        for (int ci = 0; ci < 3; ci++)
#pragma unroll
            for (int dy = 0; dy < 4; dy++) {
                int ih = ih0 + dy;
                bool rok = ((unsigned)ih < 64u);
#pragma unroll
                for (int dx = 0; dx < 4; dx++) {
                    int iw = iw0 + dx;
                    patch[ci][dy][dx] = (rok && ((unsigned)iw < 64u))
                                            ? xb[ci * 4096 + ih * 64 + iw] : 0.f;
                }
            }
        bf16x8 sv;
#pragma unroll
        for (int c8 = 0; c8 < 8; c8++) {
            int co = cog * 8 + c8;
            const float* wc = w1 + co * 27;   // wave-uniform -> s_load
            float a0 = 0.f, a1 = 0.f, a2 = 0.f, a3 = 0.f;
#pragma unroll
            for (int ci = 0; ci < 3; ci++)
#pragma unroll
                for (int ky = 0; ky < 3; ky++)
#pragma unroll
                    for (int kx = 0; kx < 3; kx++) {
                        float w = wc[ci * 9 + ky * 3 + kx];
                        a0 += w * patch[ci][ky][kx];
                        a1 += w * patch[ci][ky][kx + 1];
                        a2 += w * patch[ci][ky + 1][kx];
                        a3 += w * patch[ci][ky + 1][kx + 1];
                    }
            float s0, s1, s2, s3;
            v[c8][0] += a0; s0 = (v[c8][0] >= 1.f) ? 1.f : 0.f; if (s0 > 0.f) v[c8][0] = 0.f;
            v[c8][1] += a1; s1 = (v[c8][1] >= 1.f) ? 1.f : 0.f; if (s1 > 0.f) v[c8][1] = 0.f;
            v[c8][2] += a2; s2 = (v[c8][2] >= 1.f) ? 1.f : 0.f; if (s2 > 0.f) v[c8][2] = 0.f;
            v[c8][3] += a3; s3 = (v[c8][3] >= 1.f) ? 1.f : 0.f; if (s3 > 0.f) v[c8][3] = 0.f;
            sv[c8] = (__bf16)fmaxf(fmaxf(s0, s1), fmaxf(s2, s3));
        }
        *(bf16x8*)(spk1p + ((size_t)(t * NB + n) * 1024 + ph * 32 + pw) * 64
                         + cog * 8) = sv;
    }
}

// -------------------------------- conv2 (MFMA) + IF + maxpool fused, t in-kernel
// Block = (n, 4-row strip, co-half of 32). 4 waves: mh (h-pair) x oh (co-16).
// Per tap: B-frags from LDS (pre-split weights), A-frags direct from global
// (24 KB/t working set -> L1-resident). IF state v[4] f32x4 per lane persists
// across t. 2x2 pool is within-lane in the C-layout (w-pairs = reg pairs,
// h-pairs = i,i+2).
__global__ __launch_bounds__(256, 1) void k_conv2_if_pool(
        const short* __restrict__ spk1p,   // [256][32][32][64] bf16 bits
        const short* __restrict__ w2s,     // [2][55296] bf16 bits (frag order)
        __bf16* __restrict__ spk2) {       // [256][64][16][16]
    int b     = blockIdx.x;                // 512 = 32n * 8strip * 2ch
    int ch    = b & 1;
    int strip = (b >> 1) & 7;
    int n     = b >> 4;
    int tid   = threadIdx.x;
    int lane  = tid & 63;
    int wv    = tid >> 6;
    int mh    = wv >> 1, oh = wv & 1;
    int lm    = lane & 15, kq = lane >> 4;

    __shared__ short Bs[55296];            // 108 KB: 9tap x 2kh x 2oh x 3sp x 512
    {
        const uint4* src = (const uint4*)(w2s + (size_t)ch * 55296);
        uint4* dst = (uint4*)Bs;
        for (int i = tid; i < 6912; i += 256) dst[i] = src[i];
    }
    __syncthreads();
    const short* Bsw = Bs + oh * 1536;

    f32x4 v[4];
#pragma unroll
    for (int i = 0; i < 4; i++) v[i] = (f32x4){0.f, 0.f, 0.f, 0.f};

    int co = ch * 32 + oh * 16 + lm;
    int pH = strip * 2 + mh;
    int h0 = strip * 4 + 2 * mh - 1;       // + (i>>1) + dy gives source row

#pragma unroll 1
    for (int t = 0; t < T_STEPS; t++) {
        const short* At = spk1p + (size_t)(t * NB + n) * 65536 + kq * 8;
        f32x4 acc[4];
#pragma unroll
        for (int i = 0; i < 4; i++) acc[i] = (f32x4){0.f, 0.f, 0.f, 0.f};

#pragma unroll 1
        for (int dy = 0; dy < 3; dy++) {
#pragma unroll 1
            for (int dx = 0; dx < 3; dx++) {
                const short* bp = Bsw + (dy * 3 + dx) * 6144 + lane * 8;
                s16x8 bf[2][3];
#pragma unroll
                for (int kh = 0; kh < 2; kh++)
#pragma unroll
                    for (int sp = 0; sp < 3; sp++)
                        bf[kh][sp] = *(const s16x8*)(bp + kh * 3072 + sp * 512);
#pragma unroll
                for (int i = 0; i < 4; i++) {
                    int hh = h0 + (i >> 1) + dy;
                    int ww = (i & 1) * 16 + lm + dx - 1;
                    bool ok = ((unsigned)hh < 32u) && ((unsigned)ww < 32u);
                    s16x8 a0 = {0, 0, 0, 0, 0, 0, 0, 0};
                    s16x8 a1 = {0, 0, 0, 0, 0, 0, 0, 0};
                    if (ok) {
                        const short* ap = At + (hh * 32 + ww) * 64;
                        a0 = *(const s16x8*)ap;
                        a1 = *(const s16x8*)(ap + 32);
                    }
#pragma unroll
                    for (int sp = 0; sp < 3; sp++) {
                        acc[i] = __builtin_amdgcn_mfma_f32_16x16x32_bf16(
                            a0, bf[0][sp], acc[i], 0, 0, 0);
                        acc[i] = __builtin_amdgcn_mfma_f32_16x16x32_bf16(
                            a1, bf[1][sp], acc[i], 0, 0, 0);
                    }
                }
            }
        }
        // IF (charge, fire, hard reset) then 2x2 max-pool, all within-lane
        float s[4][4];
#pragma unroll
        for (int i = 0; i < 4; i++)
#pragma unroll
            for (int r = 0; r < 4; r++) {
                float vv = v[i][r] + acc[i][r];
                float sp = (vv >= 1.f) ? 1.f : 0.f;
                s[i][r] = sp;
                v[i][r] = (sp > 0.f) ? 0.f : vv;
            }
        __bf16* op = spk2 + ((size_t)(t * NB + n) * 64 + co) * 256 + pH * 16
                   + kq * 2;
#pragma unroll
        for (int i2 = 0; i2 < 2; i2++) {
            float p0 = fmaxf(fmaxf(s[i2][0], s[i2][1]),
                             fmaxf(s[i2 + 2][0], s[i2 + 2][1]));
            float p1 = fmaxf(fmaxf(s[i2][2], s[i2][3]),
                             fmaxf(s[i2 + 2][2], s[i2 + 2][3]));
            bf16x2 pv = {(__bf16)p0, (__bf16)p1};
            *(bf16x2*)(op + i2 * 8) = pv;
        }
    }
}

// ----------------------------------------------------------- fc1 via bf16 MFMA
__global__ __launch_bounds__(256) void k_fc1_mfma(
        const short* __restrict__ A,      // spk2 bf16 bits [256][16384]
        const float* __restrict__ W,      // fc1 [4096][16384]
        float* __restrict__ part) {       // [8][256][4096]
    int b  = blockIdx.x;
    int nt = b & 63;
    int ks = b >> 6;
    int o0 = nt * 64;
    int kbase = ks * 2048;

    __shared__ __bf16 Bs[3][2][4][64][8];   // 24 KB

    int t    = threadIdx.x;
    int lane = t & 63;
    int wv_i = t >> 6;
    int mh   = wv_i >> 1;
    int oh   = wv_i & 1;

    int orow = t >> 4;
    int k4   = (t & 15) * 4;
    int sS   = k4 >> 5;
    int kg   = (k4 >> 3) & 3;
    int ke   = k4 & 7;
    int ln   = orow + kg * 16;
    const float* wp0 = W + (size_t)(o0 + orow) * 16384 + kbase + k4;

    const short* ap0 = A + (size_t)(mh * 128 + (lane & 15)) * 16384
                         + kbase + ((lane >> 4) & 3) * 8;

    f32x4 acc[8][2];
#pragma unroll
    for (int i = 0; i < 8; i++)
#pragma unroll
        for (int oi = 0; oi < 2; oi++) acc[i][oi] = (f32x4){0.f, 0.f, 0.f, 0.f};

    float4 wv[4];
#pragma unroll
    for (int j = 0; j < 4; j++) wv[j] = *(const float4*)(wp0 + (size_t)j * 262144);

    for (int it = 0; it < 32; ++it) {
        __syncthreads();
#pragma unroll
        for (int j = 0; j < 4; j++) {
            float4 v4 = wv[j];
            Split3 sx = split3(v4.x), sy = split3(v4.y),
                   sz = split3(v4.z), sw = split3(v4.w);
            bf16x4 h4 = {(__bf16)sx.h, (__bf16)sy.h, (__bf16)sz.h, (__bf16)sw.h};
            bf16x4 m4 = {(__bf16)sx.m, (__bf16)sy.m, (__bf16)sz.m, (__bf16)sw.m};
            bf16x4 l4 = {(__bf16)sx.l, (__bf16)sy.l, (__bf16)sz.l, (__bf16)sw.l};
            *(bf16x4*)&Bs[0][sS][j][ln][ke] = h4;
            *(bf16x4*)&Bs[1][sS][j][ln][ke] = m4;
            *(bf16x4*)&Bs[2][sS][j][ln][ke] = l4;
        }
        __syncthreads();
        if (it < 31) {
#pragma unroll
            for (int j = 0; j < 4; j++)
                wv[j] = *(const float4*)(wp0 + (size_t)j * 262144 + (it + 1) * 64);
        }
        const short* ait = ap0 + it * 64;
#pragma unroll
        for (int s = 0; s < 2; ++s) {
            s16x8 bb[2][3];
#pragma unroll
            for (int oi = 0; oi < 2; oi++)
#pragma unroll
                for (int sp = 0; sp < 3; sp++)
                    bb[oi][sp] = *(const s16x8*)&Bs[sp][s][2 * oh + oi][lane][0];
            s16x8 av[8];
#pragma unroll
            for (int i = 0; i < 8; i++)
                av[i] = *(const s16x8*)(ait + s * 32 + (size_t)i * 16 * 16384);
#pragma unroll
            for (int i = 0; i < 8; i++)
#pragma unroll
                for (int oi = 0; oi < 2; oi++) {
                    acc[i][oi] = __builtin_amdgcn_mfma_f32_16x16x32_bf16(
                        av[i], bb[oi][0], acc[i][oi], 0, 0, 0);
                    acc[i][oi] = __builtin_amdgcn_mfma_f32_16x16x32_bf16(
                        av[i], bb[oi][1], acc[i][oi], 0, 0, 0);
                    acc[i][oi] = __builtin_amdgcn_mfma_f32_16x16x32_bf16(
                        av[i], bb[oi][2], acc[i][oi], 0, 0, 0);
                }
        }
    }
    int col = lane & 15;
    int rq  = (lane >> 4) * 4;
#pragma unroll
    for (int i = 0; i < 8; i++)
#pragma unroll
        for (int oi = 0; oi < 2; oi++)
#pragma unroll
            for (int r = 0; r < 4; r++) {
                int m = mh * 128 + i * 16 + rq + r;
                int o = o0 + (2 * oh + oi) * 16 + col;
                part[((size_t)ks * 256 + m) * 4096 + o] = acc[i][oi][r];
            }
}

// ----------------------------------------------- K-split reduce + IF for fc1
__global__ void k_fc1_if(const float* __restrict__ part,
                         float* __restrict__ spk3) {
    int idx = blockIdx.x * 256 + threadIdx.x;   // 131072
    int o = idx & 4095;
    int n = idx >> 12;
    float v = 0.f;
    for (int t = 0; t < T_STEPS; t++) {
        int m = t * NB + n;
        float s = 0.f;
#pragma unroll
        for (int ks = 0; ks < 8; ks++)
            s += part[((size_t)ks * 256 + m) * 4096 + o];
        v += s;
        float sp = (v >= 1.f) ? 1.f : 0.f;
        if (sp > 0.f) v = 0.f;
        spk3[(size_t)m * 4096 + o] = sp;
    }
}

// ------------------------------------------------------ fc2 + IF + time-mean
__global__ __launch_bounds__(256) void k_fc2_if_mean(
        const float* __restrict__ spk3, const float* __restrict__ fc2,
        float* __restrict__ out) {
    int b = blockIdx.x;                  // 320 = 32n * 10o
    int n = b / 10, o = b % 10;
    const float* wr = fc2 + o * 4096;
    __shared__ float red[256];
    int tid = threadIdx.x;
    float v = 0.f, cnt = 0.f;
    for (int t = 0; t < T_STEPS; t++) {
        const float* row = spk3 + (size_t)(t * NB + n) * 4096;
        float p = 0.f;
        for (int i = tid; i < 4096; i += 256) p += row[i] * wr[i];
        red[tid] = p;
        __syncthreads();
        for (int s = 128; s > 0; s >>= 1) {
            if (tid < s) red[tid] += red[tid + s];
            __syncthreads();
        }
        if (tid == 0) {
            v += red[0];
            float sp = (v >= 1.f) ? 1.f : 0.f;
            cnt += sp;
            if (sp > 0.f) v = 0.f;
        }
        __syncthreads();
    }
    if (tid == 0) out[n * 10 + o] = cnt * 0.125f;
}

// ---------------------------------------------------------------------- launch
extern "C" void kernel_launch(void* const* d_in, const int* in_sizes, int n_in,
                              void* d_out, int out_size, void* d_ws, size_t ws_size,
                              hipStream_t stream) {
    const float* x   = (const float*)d_in[0];   // [8,32,3,64,64]
    const float* w1  = (const float*)d_in[1];   // [64,3,3,3]
    const float* w2  = (const float*)d_in[2];   // [64,64,3,3]
    const float* fc1 = (const float*)d_in[3];   // [4096,16384]
    const float* fc2 = (const float*)d_in[4];   // [10,4096]
    float* out = (float*)d_out;                 // [32,10]

    float* ws = (float*)d_ws;
    // workspace layout (float slots)
    const size_t off_w2s   = 0;                          // 57344 (110592 bf16)
    const size_t off_spk1p = 57344;                      // 8388608 (16.8M bf16)
    const size_t off_spk2  = off_spk1p + 8388608;        // 2097152 (4.2M bf16)
    const size_t off_part  = off_spk2 + 2097152;         // 8388608
    const size_t off_spk3  = off_part + 8388608;         // 1048576
    __bf16* w2s   = (__bf16*)(ws + off_w2s);
    __bf16* spk1p = (__bf16*)(ws + off_spk1p);
    __bf16* spk2  = (__bf16*)(ws + off_spk2);
    float*  part  = ws + off_part;
    float*  spk3  = ws + off_spk3;

    k_w2s<<<144, 256, 0, stream>>>(w2, w2s);
    k_conv1_if_pool<<<1024, 256, 0, stream>>>(x, w1, spk1p);
    k_conv2_if_pool<<<512, 256, 0, stream>>>((const short*)spk1p,
                                             (const short*)w2s, spk2);
    k_fc1_mfma<<<512, 256, 0, stream>>>((const short*)spk2, fc1, part);
    k_fc1_if<<<512, 256, 0, stream>>>(part, spk3);
    k_fc2_if_mean<<<320, 256, 0, stream>>>(spk3, fc2, out);
}